// Round 6
// baseline (1892.150 us; speedup 1.0000x reference)
//
#include <hip/hip_runtime.h>
#include <hip/hip_bf16.h>

#define NLVL 20
#define PN   5000
#define EPLE 40000
#define FDIM 128
#define HDIM 256
#define NTOT (NLVL * PN)
#define CAP  32

#define SB() __builtin_amdgcn_sched_barrier(0)

typedef __attribute__((ext_vector_type(8))) short short8;   // 8 bf16 in 4 VGPRs
typedef __attribute__((ext_vector_type(4))) float f32x4;

__device__ __forceinline__ f32x4 mfma16(short8 a, short8 b, f32x4 c) {
  return __builtin_amdgcn_mfma_f32_16x16x32_bf16(a, b, c, 0, 0, 0);
}

__device__ __forceinline__ ushort f2b(float f) {
  union { float f; unsigned u; } v; v.f = f;
  unsigned r = v.u + 0x7FFFu + ((v.u >> 16) & 1u);   // RNE
  return (ushort)(r >> 16);
}

__device__ __forceinline__ uint2 packu2(f32x4 v) {
  union { uint2 u2; ushort s[4]; } p;
  p.s[0] = f2b(v[0]); p.s[1] = f2b(v[1]); p.s[2] = f2b(v[2]); p.s[3] = f2b(v[3]);
  return p.u2;
}

__device__ __forceinline__ f32x4 relu4(f32x4 a) {
  f32x4 o;
  o[0] = fmaxf(a[0], 0.f); o[1] = fmaxf(a[1], 0.f);
  o[2] = fmaxf(a[2], 0.f); o[3] = fmaxf(a[3], 0.f);
  return o;
}

// ---- LDS act buffers: [16 rows][256 cols] bf16, XOR-swizzled ----
__device__ __forceinline__ void st_lds8(ushort* buf, int r, int byteoff, uint2 v) {
  *(uint2*)((char*)buf + r * 512 + (byteoff ^ ((r & 7) << 4))) = v;
}
__device__ __forceinline__ short8 ld_lds16(const ushort* buf, int r, int byteoff) {
  return *(const short8*)((const char*)buf + r * 512 + (byteoff ^ ((r & 7) << 4)));
}
__device__ __forceinline__ void rdB(const ushort* buf, short8* B, int r, int g) {
  #pragma unroll
  for (int kc = 0; kc < 8; ++kc) B[kc] = ld_lds16(buf, r, 64 * kc + 16 * g);
}
__device__ __forceinline__ void wr2(ushort* buf, f32x4 a, f32x4 b, int cc0, int r, int g) {
  st_lds8(buf, r, 32 * cc0 + 8 * g, packu2(a));
  st_lds8(buf, r, 32 * (cc0 + 1) + 8 * g, packu2(b));
}
__device__ __forceinline__ void wr2add(ushort* buf, const f32x4* X, const f32x4* Y,
                                       int cc0, int r, int g) {
  st_lds8(buf, r, 32 * cc0 + 8 * g, packu2(X[0] + Y[0]));
  st_lds8(buf, r, 32 * (cc0 + 1) + 8 * g, packu2(X[1] + Y[1]));
}

// ---- register weight buffers: 16 frags = 2 col-tiles x 8 k-chunks ----
__device__ __forceinline__ void ldW(const ushort* __restrict__ base, int sk,
                                    short8* W, int cc0, int r, int g) {
  #pragma unroll
  for (int t = 0; t < 2; ++t) {
    const ushort* p = base + (size_t)(16 * (cc0 + t) + r) * sk + 8 * g;
    #pragma unroll
    for (int kc = 0; kc < 8; ++kc) W[t * 8 + kc] = *(const short8*)(p + kc * 32);
  }
}
__device__ __forceinline__ void mm8(const short8* W, const short8* B, f32x4* a) {
  #pragma unroll
  for (int t = 0; t < 2; ++t)
    #pragma unroll
    for (int kc = 0; kc < 8; ++kc)
      a[t] = mfma16(W[t * 8 + kc], B[kc], a[t]);
}

__device__ __forceinline__ void initb(const float* bias_s, int st, f32x4* a, int cc0, int g) {
  a[0] = *(const f32x4*)(bias_s + st * 256 + 16 * cc0 + 4 * g);
  a[1] = *(const f32x4*)(bias_s + st * 256 + 16 * (cc0 + 1) + 4 * g);
}

// ---------------- CSR-lite build ----------------
__global__ void fill_csr_kernel(const int* __restrict__ esrc, const int* __restrict__ edst,
                                int* __restrict__ counts, int* __restrict__ buckets) {
  int e = blockIdx.x * 256 + threadIdx.x;
  if (e >= (NLVL - 1) * EPLE) return;
  int l = e / EPLE;
  int key = l * PN + edst[e];
  int pos = atomicAdd(&counts[key], 1);
  if (pos < CAP) buckets[(size_t)key * CAP + pos] = esrc[e];
}

// ---------------- weight prep: fp32 [K][N] -> bf16 [N][K] ----------------
__global__ void prep_w(const float* __restrict__ we, const float* __restrict__ mpw,
                       const float* __restrict__ nw0, const float* __restrict__ nww,
                       ushort* __restrict__ wet, ushort* __restrict__ mpt,
                       ushort* __restrict__ ne0t, ushort* __restrict__ nwt) {
  int i = blockIdx.x * 256 + threadIdx.x;
  if (i < 256 * 128) { int n = i >> 7, k = i & 127; wet[i] = f2b(we[k * 256 + n]); }
  if (i < 4 * 65536) { int mi = i >> 16, rr = i & 65535, n = rr >> 8, k = rr & 255;
                       mpt[i] = f2b(mpw[mi * 65536 + k * 256 + n]); }
  if (i < 256 * 512) { int n = i >> 9, k = i & 511; ne0t[i] = f2b(nw0[k * 256 + n]); }
  if (i < 3 * 65536) { int mi = i >> 16, rr = i & 65535, n = rr >> 8, k = rr & 255;
                       nwt[i] = f2b(nww[mi * 65536 + k * 256 + n]); }
}

// -------- standalone embed for level-0 rows only (final outputs) --------
__global__ __launch_bounds__(256, 4) void embed0(
    const float* __restrict__ nf, const ushort* __restrict__ wet,
    const float* __restrict__ be, float* __restrict__ out) {
  const int w = threadIdx.x >> 6, lane = threadIdx.x & 63;
  const int r = lane & 15, g = lane >> 4;
  const int rowa = blockIdx.x * 128 + w * 32 + r;
  const int rowb = rowa + 16;
  const int ra = rowa < PN ? rowa : 0;
  const int rb = rowb < PN ? rowb : 0;

  short8 Ba[4], Bb[4];
  #pragma unroll
  for (int kc = 0; kc < 4; ++kc) {
    float t[8];
    f32x4 a0 = *(const f32x4*)(nf + (size_t)ra * FDIM + kc * 32 + 8 * g);
    f32x4 a1 = *(const f32x4*)(nf + (size_t)ra * FDIM + kc * 32 + 8 * g + 4);
    t[0]=a0[0]; t[1]=a0[1]; t[2]=a0[2]; t[3]=a0[3];
    t[4]=a1[0]; t[5]=a1[1]; t[6]=a1[2]; t[7]=a1[3];
    short8 o;
    #pragma unroll
    for (int i = 0; i < 8; ++i) o[i] = (short)f2b(t[i]);
    Ba[kc] = o;
    f32x4 b0 = *(const f32x4*)(nf + (size_t)rb * FDIM + kc * 32 + 8 * g);
    f32x4 b1 = *(const f32x4*)(nf + (size_t)rb * FDIM + kc * 32 + 8 * g + 4);
    t[0]=b0[0]; t[1]=b0[1]; t[2]=b0[2]; t[3]=b0[3];
    t[4]=b1[0]; t[5]=b1[1]; t[6]=b1[2]; t[7]=b1[3];
    #pragma unroll
    for (int i = 0; i < 8; ++i) o[i] = (short)f2b(t[i]);
    Bb[kc] = o;
  }
  #pragma unroll
  for (int cc = 0; cc < 16; ++cc) {
    f32x4 bias = *(const f32x4*)(be + 16 * cc + 4 * g);
    f32x4 aa = bias, ab = bias;
    #pragma unroll
    for (int kc = 0; kc < 4; ++kc) {
      short8 wv = *(const short8*)(wet + (size_t)(16 * cc + r) * FDIM + kc * 32 + 8 * g);
      aa = mfma16(wv, Ba[kc], aa);
      ab = mfma16(wv, Bb[kc], ab);
    }
    if (rowa < PN) {
      f32x4 o; o[0]=tanhf(aa[0]); o[1]=tanhf(aa[1]); o[2]=tanhf(aa[2]); o[3]=tanhf(aa[3]);
      *(f32x4*)(out + (size_t)rowa * HDIM + 16 * cc + 4 * g) = o;
    }
    if (rowb < PN) {
      f32x4 o; o[0]=tanhf(ab[0]); o[1]=tanhf(ab[1]); o[2]=tanhf(ab[2]); o[3]=tanhf(ab[3]);
      *(f32x4*)(out + (size_t)rowb * HDIM + 16 * cc + 4 * g) = o;
    }
  }
}

// ------- fused per-level chain: 16 rows/block, 8 waves split 256 cols -------
// register double-buffered weight prefetch, PINNED with sched_barrier(0) so
// the compiler cannot sink the 16-load batch down to its uses (R5 failure:
// VGPR_Count=64 proved the buffers were eliminated).
__global__ __launch_bounds__(512, 2) void level_mfma(
    float* __restrict__ eb, const float* __restrict__ nf,
    const int* __restrict__ counts, const int* __restrict__ buckets,
    const ushort* __restrict__ wet,
    const ushort* __restrict__ mpt, const ushort* __restrict__ ne0t,
    const ushort* __restrict__ nwt,
    const float* __restrict__ be, const float* __restrict__ mpb,
    const float* __restrict__ neb0, const float* __restrict__ neb, int l) {
  __shared__ ushort Bs[4][16 * 256];
  __shared__ float bias_s[9 * 256];
  __shared__ int cnt_s[16];
  const int tid = threadIdx.x, w = tid >> 6, lane = tid & 63;
  const int r = lane & 15, g = lane >> 4;
  const int p0 = blockIdx.x * 16;
  const int cc0 = 2 * w;

  short8 WA[16], WB[16];
  short8 B[8], B2[8];
  f32x4 X[2], Y[2], Z[2], a[2];

  // prefetch S1 weights (mp_w[0]) -> WA as early as possible
  ldW(mpt, 256, WA, cc0, r, g);
  SB();

  // bias table -> LDS (slot: 0=be, 1..4=mp_b, 5=ne_b0, 6..8=ne_b)
  for (int i = tid; i < 2304; i += 512) {
    float v;
    if (i < 256) v = be[i];
    else if (i < 1280) v = mpb[i - 256];
    else if (i < 1536) v = neb0[i - 1280];
    else v = neb[i - 1536];
    bias_s[i] = v;
  }
  if (tid < 16) {
    int p = p0 + tid;
    cnt_s[tid] = (p < PN) ? min(counts[l * PN + p], CAP) : 0;
  }
  __syncthreads();

  // ---- phase 0: embed -> Bs3 ; gather -> Bs0 ----
  {
    // embed weights (K=128: 2 tiles x 4 kc) -> WB[0..7]
    #pragma unroll
    for (int t = 0; t < 2; ++t) {
      const ushort* p = wet + (size_t)(16 * (cc0 + t) + r) * FDIM + 8 * g;
      #pragma unroll
      for (int kc = 0; kc < 4; ++kc) WB[t * 4 + kc] = *(const short8*)(p + kc * 32);
    }
    const float* nfr = nf + (size_t)((l + 1) * PN + (p0 + r < PN ? p0 + r : 0)) * FDIM;
    short8 Bn[4];
    #pragma unroll
    for (int kc = 0; kc < 4; ++kc) {
      f32x4 a0 = *(const f32x4*)(nfr + kc * 32 + 8 * g);
      f32x4 a1 = *(const f32x4*)(nfr + kc * 32 + 8 * g + 4);
      float t[8];
      t[0]=a0[0]; t[1]=a0[1]; t[2]=a0[2]; t[3]=a0[3];
      t[4]=a1[0]; t[5]=a1[1]; t[6]=a1[2]; t[7]=a1[3];
      short8 o;
      #pragma unroll
      for (int i = 0; i < 8; ++i) o[i] = (short)f2b(t[i]);
      Bn[kc] = o;
    }
    initb(bias_s, 0, a, cc0, g);
    #pragma unroll
    for (int t = 0; t < 2; ++t)
      #pragma unroll
      for (int kc = 0; kc < 4; ++kc)
        a[t] = mfma16(WB[t * 4 + kc], Bn[kc], a[t]);
    f32x4 t0, t1;
    t0[0]=tanhf(a[0][0]); t0[1]=tanhf(a[0][1]); t0[2]=tanhf(a[0][2]); t0[3]=tanhf(a[0][3]);
    t1[0]=tanhf(a[1][0]); t1[1]=tanhf(a[1][1]); t1[2]=tanhf(a[1][2]); t1[3]=tanhf(a[1][3]);
    wr2(Bs[3], t0, t1, cc0, r, g);

    // gather: wave w sums rows 2w, 2w+1 with whole-wave coalesced 1KB loads
    const int r0 = 2 * w, r1 = r0 + 1;
    const int c0 = cnt_s[r0], c1 = cnt_s[r1];
    const int* bk0 = buckets + (size_t)(l * PN + (p0 + r0 < PN ? p0 + r0 : 0)) * CAP;
    const int* bk1 = buckets + (size_t)(l * PN + (p0 + r1 < PN ? p0 + r1 : 0)) * CAP;
    f32x4 s0 = {0,0,0,0}, s1 = {0,0,0,0};
    int mx = c0 > c1 ? c0 : c1;
    for (int j = 0; j < mx; ++j) {
      if (j < c0) s0 += *(const f32x4*)(eb + (size_t)bk0[j] * HDIM + 4 * lane);
      if (j < c1) s1 += *(const f32x4*)(eb + (size_t)bk1[j] * HDIM + 4 * lane);
    }
    st_lds8(Bs[0], r0, 8 * lane, packu2(s0));
    st_lds8(Bs[0], r1, 8 * lane, packu2(s1));
  }
  __syncthreads();

  // S1: t0                                [uses WA, prefetch S2 -> WB, pinned]
  ldW(mpt + 65536, 256, WB, cc0, r, g);
  SB();
  rdB(Bs[0], B, r, g);
  initb(bias_s, 1, a, cc0, g);
  mm8(WA, B, a);
  X[0] = relu4(a[0]); X[1] = relu4(a[1]);
  wr2(Bs[1], X[0], X[1], cc0, r, g);
  __syncthreads();

  // S2: u1                                [uses WB, prefetch S3 -> WA, pinned]
  ldW(mpt + 131072, 256, WA, cc0, r, g);
  SB();
  rdB(Bs[1], B, r, g);
  initb(bias_s, 2, a, cc0, g);
  mm8(WB, B, a);
  Y[0] = relu4(a[0]); Y[1] = relu4(a[1]);
  wr2add(Bs[2], X, Y, cc0, r, g);                       // t0+u1
  __syncthreads();

  // S3: u2                                [uses WA, prefetch S4 -> WB, pinned]
  ldW(mpt + 196608, 256, WB, cc0, r, g);
  SB();
  rdB(Bs[2], B, r, g);
  initb(bias_s, 3, a, cc0, g);
  mm8(WA, B, a);
  Z[0] = relu4(a[0]); Z[1] = relu4(a[1]);
  wr2add(Bs[0], Y, Z, cc0, r, g);                       // u1+u2
  __syncthreads();

  // S4: mr                                [uses WB, prefetch S5 h1 -> WA, pinned]
  ldW(ne0t, 512, WA, cc0, r, g);
  SB();
  rdB(Bs[0], B, r, g);
  initb(bias_s, 4, a, cc0, g);
  mm8(WB, B, a);
  X[0] = relu4(a[0]); X[1] = relu4(a[1]);
  wr2(Bs[1], X[0], X[1], cc0, r, g);                    // mr
  __syncthreads();

  // S5: x0 = relu([base | mr] @ ne_w0)
  //   h2 -> WB pinned at top; S6 prefetch -> WA pinned AFTER mm8(WA) so WA is
  //   dead first (keeps liveness ~170 VGPR, no spill at 256 cap)
  ldW(ne0t + 256, 512, WB, cc0, r, g);                  // half2 (k 256..511)
  SB();
  rdB(Bs[3], B2, r, g);                                 // base
  rdB(Bs[1], B, r, g);                                  // mr
  initb(bias_s, 5, a, cc0, g);
  mm8(WA, B2, a);                                       // k 0..255
  SB();
  ldW(nwt, 256, WA, cc0, r, g);                         // prefetch S6
  SB();
  mm8(WB, B, a);                                        // k 256..511
  Y[0] = relu4(a[0]); Y[1] = relu4(a[1]);
  wr2(Bs[0], Y[0], Y[1], cc0, r, g);                    // x0
  __syncthreads();

  // S6: v1                                [uses WA, prefetch S7 -> WB, pinned]
  ldW(nwt + 65536, 256, WB, cc0, r, g);
  SB();
  rdB(Bs[0], B, r, g);
  initb(bias_s, 6, a, cc0, g);
  mm8(WA, B, a);
  Z[0] = relu4(a[0]); Z[1] = relu4(a[1]);
  wr2add(Bs[2], Y, Z, cc0, r, g);                       // x0+v1
  __syncthreads();

  // S7: v2                                [uses WB, prefetch S8 -> WA, pinned]
  ldW(nwt + 131072, 256, WA, cc0, r, g);
  SB();
  rdB(Bs[2], B, r, g);
  initb(bias_s, 7, a, cc0, g);
  mm8(WB, B, a);
  X[0] = relu4(a[0]); X[1] = relu4(a[1]);
  wr2add(Bs[1], Z, X, cc0, r, g);                       // v1+v2
  __syncthreads();

  // S8: out                               [uses WA]
  rdB(Bs[1], B, r, g);
  initb(bias_s, 8, a, cc0, g);
  mm8(WA, B, a);
  if (p0 + r < PN) {
    float* og = eb + ((size_t)((l + 1) * PN) + p0 + r) * HDIM;
    *(f32x4*)(og + 16 * cc0 + 4 * g)       = relu4(a[0]);
    *(f32x4*)(og + 16 * (cc0 + 1) + 4 * g) = relu4(a[1]);
  }
}

// ---------------- launch ----------------
extern "C" void kernel_launch(void* const* d_in, const int* in_sizes, int n_in,
                              void* d_out, int out_size, void* d_ws, size_t ws_size,
                              hipStream_t stream) {
  (void)in_sizes; (void)n_in; (void)out_size; (void)ws_size;
  const float* nf      = (const float*)d_in[0];
  const float* W_embed = (const float*)d_in[1];
  const float* b_embed = (const float*)d_in[2];
  const float* mp_w    = (const float*)d_in[3];
  const float* mp_b    = (const float*)d_in[4];
  const float* ne_w0   = (const float*)d_in[5];
  const float* ne_b0   = (const float*)d_in[6];
  const float* ne_w    = (const float*)d_in[7];
  const float* ne_b    = (const float*)d_in[8];
  const int*   esrc    = (const int*)d_in[9];
  const int*   edst    = (const int*)d_in[10];
  float* out = (float*)d_out;

  int*    counts  = (int*)d_ws;                                 // 95000 ints
  int*    buckets = (int*)((char*)d_ws + (512 << 10));          // 95000*32 ints (~12.2MB)
  ushort* wet     = (ushort*)((char*)d_ws + (13u << 20));       // bf16 weights, transposed
  ushort* mpt     = wet + 256 * 128;
  ushort* ne0t    = mpt + 4 * 65536;
  ushort* nwt     = ne0t + 256 * 512;

  hipMemsetAsync(counts, 0, (NLVL - 1) * PN * sizeof(int), stream);
  fill_csr_kernel<<<((NLVL - 1) * EPLE + 255) / 256, 256, 0, stream>>>(esrc, edst, counts, buckets);
  prep_w<<<1024, 256, 0, stream>>>(W_embed, mp_w, ne_w0, ne_w, wet, mpt, ne0t, nwt);
  embed0<<<(PN + 127) / 128, 256, 0, stream>>>(nf, wet, b_embed, out);
  for (int l = 0; l < NLVL - 1; ++l) {
    level_mfma<<<(PN + 15) / 16, 512, 0, stream>>>(out, nf, counts, buckets,
                                                   wet, mpt, ne0t, nwt,
                                                   b_embed, mp_b, ne_b0, ne_b, l);
  }
}

// Round 7
// 1247.894 us; speedup vs baseline: 1.5163x; 1.5163x over previous
//
#include <hip/hip_runtime.h>
#include <hip/hip_bf16.h>

#define NLVL 20
#define PN   5000
#define EPLE 40000
#define FDIM 128
#define HDIM 256
#define NTOT (NLVL * PN)
#define CAP  32
#define ROWS 32

#define STR_(x) #x
// volatile asm load: compiler cannot sink/elide it (R5/R6 failure mode)
#define GLD(dst, ptr, IMM) \
  asm volatile("global_load_dwordx4 %0, %1, off offset:" STR_(IMM) : "=v"(dst) : "v"(ptr))
// counted vmcnt wait + sched fence (rule 18: MFMA hoists past asm waitcnt otherwise)
#define WAITVM(N) do { asm volatile("s_waitcnt vmcnt(" STR_(N) ")" ::: "memory"); \
                       __builtin_amdgcn_sched_barrier(0); } while (0)
// raw barrier with LDS drain only -- does NOT drain vmcnt, so weight prefetch
// stays in flight across stage boundaries (unlike __syncthreads)
#define LBAR() do { asm volatile("s_waitcnt lgkmcnt(0)\n\ts_barrier" ::: "memory"); \
                    __builtin_amdgcn_sched_barrier(0); } while (0)

typedef __attribute__((ext_vector_type(8))) short short8;   // 8 bf16 in 4 VGPRs
typedef __attribute__((ext_vector_type(4))) float f32x4;

__device__ __forceinline__ f32x4 mfma16(short8 a, short8 b, f32x4 c) {
  return __builtin_amdgcn_mfma_f32_16x16x32_bf16(a, b, c, 0, 0, 0);
}

__device__ __forceinline__ ushort f2b(float f) {
  union { float f; unsigned u; } v; v.f = f;
  unsigned r = v.u + 0x7FFFu + ((v.u >> 16) & 1u);   // RNE
  return (ushort)(r >> 16);
}

__device__ __forceinline__ uint2 packu2(f32x4 v) {
  union { uint2 u2; ushort s[4]; } p;
  p.s[0] = f2b(v[0]); p.s[1] = f2b(v[1]); p.s[2] = f2b(v[2]); p.s[3] = f2b(v[3]);
  return p.u2;
}

__device__ __forceinline__ f32x4 relu4(f32x4 a) {
  f32x4 o;
  o[0] = fmaxf(a[0], 0.f); o[1] = fmaxf(a[1], 0.f);
  o[2] = fmaxf(a[2], 0.f); o[3] = fmaxf(a[3], 0.f);
  return o;
}

// ---- LDS act buffers: [32 rows][256 cols] bf16, XOR-swizzled ----
__device__ __forceinline__ void st_lds8(ushort* buf, int row, int byteoff, uint2 v) {
  *(uint2*)((char*)buf + row * 512 + (byteoff ^ ((row & 7) << 4))) = v;
}
__device__ __forceinline__ short8 ld_lds16(const ushort* buf, int row, int byteoff) {
  return *(const short8*)((const char*)buf + row * 512 + (byteoff ^ ((row & 7) << 4)));
}

// ---- per-stage register fragments ----
// weights W[16]: [2 col-tiles][8 kc]; B half: [2 row-groups][4 kc]
__device__ __forceinline__ void ldw_asm(const ushort* __restrict__ Wt, int sk,
                                        short8* W, int cc0, int r, int g) {
  const ushort* pa = Wt + (size_t)(16 * cc0 + r) * sk + 8 * g;
  const ushort* pb = Wt + (size_t)(16 * (cc0 + 1) + r) * sk + 8 * g;
  GLD(W[0], pa, 0);   GLD(W[1], pa, 64);  GLD(W[2], pa, 128); GLD(W[3], pa, 192);
  GLD(W[4], pa, 256); GLD(W[5], pa, 320); GLD(W[6], pa, 384); GLD(W[7], pa, 448);
  GLD(W[8], pb, 0);   GLD(W[9], pb, 64);  GLD(W[10], pb, 128);GLD(W[11], pb, 192);
  GLD(W[12], pb, 256);GLD(W[13], pb, 320);GLD(W[14], pb, 384);GLD(W[15], pb, 448);
}

__device__ __forceinline__ void rdBh(const ushort* buf, short8 B[2][4], int h, int r, int g) {
  #pragma unroll
  for (int rg = 0; rg < 2; ++rg)
    #pragma unroll
    for (int kc = 0; kc < 4; ++kc)
      B[rg][kc] = ld_lds16(buf, rg * 16 + r, 64 * (h * 4 + kc) + 16 * g);
}

__device__ __forceinline__ void mmhalf(const short8* W, short8 B[2][4],
                                       f32x4 acc[2][2], int h) {
  #pragma unroll
  for (int ct = 0; ct < 2; ++ct)
    #pragma unroll
    for (int rg = 0; rg < 2; ++rg)
      #pragma unroll
      for (int kc = 0; kc < 4; ++kc)
        acc[ct][rg] = mfma16(W[ct * 8 + h * 4 + kc], B[rg][kc], acc[ct][rg]);
}

__device__ __forceinline__ void stage_mm(const short8* W, const ushort* inbuf,
                                         const float* bias_s, int slot,
                                         f32x4 acc[2][2], int r, int g, int cc0) {
  #pragma unroll
  for (int ct = 0; ct < 2; ++ct) {
    f32x4 b = *(const f32x4*)(bias_s + slot * 256 + 16 * (cc0 + ct) + 4 * g);
    acc[ct][0] = b; acc[ct][1] = b;
  }
  short8 B[2][4];
  rdBh(inbuf, B, 0, r, g);
  mmhalf(W, B, acc, 0);
  rdBh(inbuf, B, 1, r, g);
  mmhalf(W, B, acc, 1);
}

__device__ __forceinline__ void relu_acc(f32x4 a[2][2]) {
  #pragma unroll
  for (int ct = 0; ct < 2; ++ct)
    #pragma unroll
    for (int rg = 0; rg < 2; ++rg) a[ct][rg] = relu4(a[ct][rg]);
}
__device__ __forceinline__ void wr_acc(ushort* buf, f32x4 a[2][2], int cc0, int r, int g) {
  #pragma unroll
  for (int ct = 0; ct < 2; ++ct)
    #pragma unroll
    for (int rg = 0; rg < 2; ++rg)
      st_lds8(buf, rg * 16 + r, 32 * (cc0 + ct) + 8 * g, packu2(a[ct][rg]));
}
__device__ __forceinline__ void wr_acc_add(ushort* buf, f32x4 a[2][2], f32x4 x[2][2],
                                           int cc0, int r, int g) {
  #pragma unroll
  for (int ct = 0; ct < 2; ++ct)
    #pragma unroll
    for (int rg = 0; rg < 2; ++rg)
      st_lds8(buf, rg * 16 + r, 32 * (cc0 + ct) + 8 * g, packu2(a[ct][rg] + x[ct][rg]));
}
__device__ __forceinline__ void cp_acc(f32x4 d[2][2], f32x4 s[2][2]) {
  #pragma unroll
  for (int ct = 0; ct < 2; ++ct)
    #pragma unroll
    for (int rg = 0; rg < 2; ++rg) d[ct][rg] = s[ct][rg];
}

// ---------------- CSR-lite build ----------------
__global__ void fill_csr_kernel(const int* __restrict__ esrc, const int* __restrict__ edst,
                                int* __restrict__ counts, int* __restrict__ buckets) {
  int e = blockIdx.x * 256 + threadIdx.x;
  if (e >= (NLVL - 1) * EPLE) return;
  int l = e / EPLE;
  int key = l * PN + edst[e];
  int pos = atomicAdd(&counts[key], 1);
  if (pos < CAP) buckets[(size_t)key * CAP + pos] = esrc[e];
}

// ---------------- weight prep: fp32 [K][N] -> bf16 [N][K] ----------------
__global__ void prep_w(const float* __restrict__ we, const float* __restrict__ mpw,
                       const float* __restrict__ nw0, const float* __restrict__ nww,
                       ushort* __restrict__ wet, ushort* __restrict__ mpt,
                       ushort* __restrict__ ne0t, ushort* __restrict__ nwt) {
  int i = blockIdx.x * 256 + threadIdx.x;
  if (i < 256 * 128) { int n = i >> 7, k = i & 127; wet[i] = f2b(we[k * 256 + n]); }
  if (i < 4 * 65536) { int mi = i >> 16, rr = i & 65535, n = rr >> 8, k = rr & 255;
                       mpt[i] = f2b(mpw[mi * 65536 + k * 256 + n]); }
  if (i < 256 * 512) { int n = i >> 9, k = i & 511; ne0t[i] = f2b(nw0[k * 256 + n]); }
  if (i < 3 * 65536) { int mi = i >> 16, rr = i & 65535, n = rr >> 8, k = rr & 255;
                       nwt[i] = f2b(nww[mi * 65536 + k * 256 + n]); }
}

// -------- standalone embed for level-0 rows only (final outputs) --------
__global__ __launch_bounds__(256, 4) void embed0(
    const float* __restrict__ nf, const ushort* __restrict__ wet,
    const float* __restrict__ be, float* __restrict__ out) {
  const int w = threadIdx.x >> 6, lane = threadIdx.x & 63;
  const int r = lane & 15, g = lane >> 4;
  const int rowa = blockIdx.x * 128 + w * 32 + r;
  const int rowb = rowa + 16;
  const int ra = rowa < PN ? rowa : 0;
  const int rb = rowb < PN ? rowb : 0;

  short8 Ba[4], Bb[4];
  #pragma unroll
  for (int kc = 0; kc < 4; ++kc) {
    float t[8];
    f32x4 a0 = *(const f32x4*)(nf + (size_t)ra * FDIM + kc * 32 + 8 * g);
    f32x4 a1 = *(const f32x4*)(nf + (size_t)ra * FDIM + kc * 32 + 8 * g + 4);
    t[0]=a0[0]; t[1]=a0[1]; t[2]=a0[2]; t[3]=a0[3];
    t[4]=a1[0]; t[5]=a1[1]; t[6]=a1[2]; t[7]=a1[3];
    short8 o;
    #pragma unroll
    for (int i = 0; i < 8; ++i) o[i] = (short)f2b(t[i]);
    Ba[kc] = o;
    f32x4 b0 = *(const f32x4*)(nf + (size_t)rb * FDIM + kc * 32 + 8 * g);
    f32x4 b1 = *(const f32x4*)(nf + (size_t)rb * FDIM + kc * 32 + 8 * g + 4);
    t[0]=b0[0]; t[1]=b0[1]; t[2]=b0[2]; t[3]=b0[3];
    t[4]=b1[0]; t[5]=b1[1]; t[6]=b1[2]; t[7]=b1[3];
    #pragma unroll
    for (int i = 0; i < 8; ++i) o[i] = (short)f2b(t[i]);
    Bb[kc] = o;
  }
  #pragma unroll
  for (int cc = 0; cc < 16; ++cc) {
    f32x4 bias = *(const f32x4*)(be + 16 * cc + 4 * g);
    f32x4 aa = bias, ab = bias;
    #pragma unroll
    for (int kc = 0; kc < 4; ++kc) {
      short8 wv = *(const short8*)(wet + (size_t)(16 * cc + r) * FDIM + kc * 32 + 8 * g);
      aa = mfma16(wv, Ba[kc], aa);
      ab = mfma16(wv, Bb[kc], ab);
    }
    if (rowa < PN) {
      f32x4 o; o[0]=tanhf(aa[0]); o[1]=tanhf(aa[1]); o[2]=tanhf(aa[2]); o[3]=tanhf(aa[3]);
      *(f32x4*)(out + (size_t)rowa * HDIM + 16 * cc + 4 * g) = o;
    }
    if (rowb < PN) {
      f32x4 o; o[0]=tanhf(ab[0]); o[1]=tanhf(ab[1]); o[2]=tanhf(ab[2]); o[3]=tanhf(ab[3]);
      *(f32x4*)(out + (size_t)rowb * HDIM + 16 * cc + 4 * g) = o;
    }
  }
}

// ------- fused per-level chain: 32 rows/block, 8 waves x (2 col-tiles x 2 rg) -------
// grid 157 = 1 block/CU (no tail); asm weight prefetch with counted vmcnt across
// raw s_barriers (prefetch survives barriers -- __syncthreads would drain it).
__global__ __launch_bounds__(512, 2) void level_mfma(
    float* __restrict__ eb, const float* __restrict__ nf,
    const int* __restrict__ counts, const int* __restrict__ buckets,
    const ushort* __restrict__ wet,
    const ushort* __restrict__ mpt, const ushort* __restrict__ ne0t,
    const ushort* __restrict__ nwt,
    const float* __restrict__ be, const float* __restrict__ mpb,
    const float* __restrict__ neb0, const float* __restrict__ neb, int l) {
  __shared__ ushort Bs[4][ROWS * 256];
  __shared__ float bias_s[8 * 256];
  const int tid = threadIdx.x, w = tid >> 6, lane = tid & 63;
  const int r = lane & 15, g = lane >> 4;
  const int p0 = blockIdx.x * ROWS;
  const int cc0 = 2 * w;
  const int lP = l * PN;

  short8 WA[16], WB[16], WE[8];
  f32x4 acc[2][2], X[2][2];

  // ---- issue embed weights + S1 weights FIRST (land under phase-0 gather) ----
  {
    const ushort* pe0 = wet + (size_t)(16 * cc0 + r) * FDIM + 8 * g;
    const ushort* pe1 = wet + (size_t)(16 * (cc0 + 1) + r) * FDIM + 8 * g;
    GLD(WE[0], pe0, 0); GLD(WE[1], pe0, 64); GLD(WE[2], pe0, 128); GLD(WE[3], pe0, 192);
    GLD(WE[4], pe1, 0); GLD(WE[5], pe1, 64); GLD(WE[6], pe1, 128); GLD(WE[7], pe1, 192);
  }
  ldw_asm(mpt, 256, WA, cc0, r, g);                    // S1 weights

  // bias table -> LDS (slots: 0..3 mp_b, 4 ne_b0, 5..7 ne_b)
  for (int i = tid; i < 2048; i += 512) {
    float v;
    if (i < 1024) v = mpb[i];
    else if (i < 1280) v = neb0[i - 1024];
    else v = neb[i - 1280];
    bias_s[i] = v;
  }

  // ---- phase 0: gather (4 rows/wave, 4 interleaved chains) -> Bs0 ----
  {
    const int qb = 4 * w;
    f32x4 s[4]; int cnt[4]; const int* bk[4];
    #pragma unroll
    for (int i = 0; i < 4; ++i) {
      int p = p0 + qb + i;
      int pc = p < PN ? p : PN - 1;
      cnt[i] = p < PN ? min(counts[lP + p], CAP) : 0;
      bk[i] = buckets + (size_t)(lP + pc) * CAP;
      s[i][0]=0.f; s[i][1]=0.f; s[i][2]=0.f; s[i][3]=0.f;
    }
    int mx = max(max(cnt[0], cnt[1]), max(cnt[2], cnt[3]));
    for (int j = 0; j < mx; ++j) {
      #pragma unroll
      for (int i = 0; i < 4; ++i)
        if (j < cnt[i]) s[i] += *(const f32x4*)(eb + (size_t)bk[i][j] * HDIM + 4 * lane);
    }
    #pragma unroll
    for (int i = 0; i < 4; ++i)
      st_lds8(Bs[0], qb + i, 8 * lane, packu2(s[i]));
  }

  // ---- fused embed: base = tanh(nf @ We + be) -> Bs3 ----
  {
    short8 Bn[2][4];
    #pragma unroll
    for (int rg = 0; rg < 2; ++rg) {
      int p = p0 + rg * 16 + r;
      const float* nfr = nf + (size_t)((l + 1) * PN + (p < PN ? p : PN - 1)) * FDIM;
      #pragma unroll
      for (int kc = 0; kc < 4; ++kc) {
        f32x4 a0 = *(const f32x4*)(nfr + kc * 32 + 8 * g);
        f32x4 a1 = *(const f32x4*)(nfr + kc * 32 + 8 * g + 4);
        float t[8];
        t[0]=a0[0]; t[1]=a0[1]; t[2]=a0[2]; t[3]=a0[3];
        t[4]=a1[0]; t[5]=a1[1]; t[6]=a1[2]; t[7]=a1[3];
        short8 o;
        #pragma unroll
        for (int i = 0; i < 8; ++i) o[i] = (short)f2b(t[i]);
        Bn[rg][kc] = o;
      }
    }
    f32x4 b0 = *(const f32x4*)(be + 16 * cc0 + 4 * g);
    f32x4 b1 = *(const f32x4*)(be + 16 * (cc0 + 1) + 4 * g);
    acc[0][0] = b0; acc[0][1] = b0; acc[1][0] = b1; acc[1][1] = b1;
    WAITVM(0);                                          // WE landed (oldest)
    #pragma unroll
    for (int ct = 0; ct < 2; ++ct)
      #pragma unroll
      for (int rg = 0; rg < 2; ++rg)
        #pragma unroll
        for (int kc = 0; kc < 4; ++kc)
          acc[ct][rg] = mfma16(WE[ct * 4 + kc], Bn[rg][kc], acc[ct][rg]);
    #pragma unroll
    for (int ct = 0; ct < 2; ++ct)
      #pragma unroll
      for (int rg = 0; rg < 2; ++rg) {
        f32x4 o;
        o[0]=tanhf(acc[ct][rg][0]); o[1]=tanhf(acc[ct][rg][1]);
        o[2]=tanhf(acc[ct][rg][2]); o[3]=tanhf(acc[ct][rg][3]);
        st_lds8(Bs[3], rg * 16 + r, 32 * (cc0 + ct) + 8 * g, packu2(o));
      }
  }
  LBAR();

  // ---- S1: t0 = relu(W0 msgs) ---- [use WA(mp0); issue WB=mp1]
  ldw_asm(mpt + 65536, 256, WB, cc0, r, g);
  WAITVM(16);
  stage_mm(WA, Bs[0], bias_s, 0, acc, r, g, cc0);
  relu_acc(acc);
  wr_acc(Bs[1], acc, cc0, r, g);
  cp_acc(X, acc);
  LBAR();

  // ---- S2: u1 ---- [use WB(mp1); issue WA=mp2]
  ldw_asm(mpt + 131072, 256, WA, cc0, r, g);
  WAITVM(16);
  stage_mm(WB, Bs[1], bias_s, 1, acc, r, g, cc0);
  relu_acc(acc);
  wr_acc_add(Bs[2], acc, X, cc0, r, g);                 // t0+u1
  cp_acc(X, acc);                                       // keep u1
  LBAR();

  // ---- S3: u2 ---- [use WA(mp2); issue WB=mp3]
  ldw_asm(mpt + 196608, 256, WB, cc0, r, g);
  WAITVM(16);
  stage_mm(WA, Bs[2], bias_s, 2, acc, r, g, cc0);
  relu_acc(acc);
  wr_acc_add(Bs[0], acc, X, cc0, r, g);                 // u1+u2
  LBAR();

  // ---- S4: mr ---- [use WB(mp3); issue WA=ne0.h1]
  ldw_asm(ne0t, 512, WA, cc0, r, g);
  WAITVM(16);
  stage_mm(WB, Bs[0], bias_s, 3, acc, r, g, cc0);
  relu_acc(acc);
  wr_acc(Bs[1], acc, cc0, r, g);                        // mr
  LBAR();

  // ---- S5: x0 = relu([base|mr] @ ne_w0) ---- [h1 in WA; issue h2 -> WB]
  ldw_asm(ne0t + 256, 512, WB, cc0, r, g);
  WAITVM(16);                                           // h1 landed
  {
    #pragma unroll
    for (int ct = 0; ct < 2; ++ct) {
      f32x4 b = *(const f32x4*)(bias_s + 4 * 256 + 16 * (cc0 + ct) + 4 * g);
      acc[ct][0] = b; acc[ct][1] = b;
    }
    short8 B[2][4];
    rdBh(Bs[3], B, 0, r, g); mmhalf(WA, B, acc, 0);     // base k 0..127
    rdBh(Bs[3], B, 1, r, g); mmhalf(WA, B, acc, 1);     // base k 128..255
    WAITVM(0);                                          // h2 landed
    rdBh(Bs[1], B, 0, r, g); mmhalf(WB, B, acc, 0);     // mr k 0..127
    rdBh(Bs[1], B, 1, r, g); mmhalf(WB, B, acc, 1);     // mr k 128..255
  }
  ldw_asm(nwt, 256, WA, cc0, r, g);                     // issue S6 late (h1 dead)
  relu_acc(acc);
  wr_acc(Bs[2], acc, cc0, r, g);                        // x0
  cp_acc(X, acc);                                       // keep x0
  LBAR();

  // ---- S6: v1 ---- [use WA(nw0); issue WB=nw1]
  ldw_asm(nwt + 65536, 256, WB, cc0, r, g);
  WAITVM(16);                                           // waits WA (nw1 is newest 16)
  stage_mm(WA, Bs[2], bias_s, 5, acc, r, g, cc0);
  relu_acc(acc);
  wr_acc_add(Bs[0], acc, X, cc0, r, g);                 // x0+v1
  cp_acc(X, acc);                                       // keep v1
  LBAR();

  // ---- S7: v2 ---- [use WB(nw1); issue WA=nw2]
  ldw_asm(nwt + 131072, 256, WA, cc0, r, g);
  WAITVM(16);
  stage_mm(WB, Bs[0], bias_s, 6, acc, r, g, cc0);
  relu_acc(acc);
  wr_acc_add(Bs[1], acc, X, cc0, r, g);                 // v1+v2
  LBAR();

  // ---- S8: out ---- [use WA(nw2)]
  WAITVM(0);
  stage_mm(WA, Bs[1], bias_s, 7, acc, r, g, cc0);
  relu_acc(acc);
  #pragma unroll
  for (int rg = 0; rg < 2; ++rg) {
    int p = p0 + rg * 16 + r;
    if (p < PN) {
      float* og = eb + ((size_t)((l + 1) * PN) + p) * HDIM;
      *(f32x4*)(og + 16 * cc0 + 4 * g)       = acc[0][rg];
      *(f32x4*)(og + 16 * (cc0 + 1) + 4 * g) = acc[1][rg];
    }
  }
}

// ---------------- launch ----------------
extern "C" void kernel_launch(void* const* d_in, const int* in_sizes, int n_in,
                              void* d_out, int out_size, void* d_ws, size_t ws_size,
                              hipStream_t stream) {
  (void)in_sizes; (void)n_in; (void)out_size; (void)ws_size;
  const float* nf      = (const float*)d_in[0];
  const float* W_embed = (const float*)d_in[1];
  const float* b_embed = (const float*)d_in[2];
  const float* mp_w    = (const float*)d_in[3];
  const float* mp_b    = (const float*)d_in[4];
  const float* ne_w0   = (const float*)d_in[5];
  const float* ne_b0   = (const float*)d_in[6];
  const float* ne_w    = (const float*)d_in[7];
  const float* ne_b    = (const float*)d_in[8];
  const int*   esrc    = (const int*)d_in[9];
  const int*   edst    = (const int*)d_in[10];
  float* out = (float*)d_out;

  int*    counts  = (int*)d_ws;                                 // 95000 ints
  int*    buckets = (int*)((char*)d_ws + (512 << 10));          // 95000*32 ints (~12.2MB)
  ushort* wet     = (ushort*)((char*)d_ws + (13u << 20));       // bf16 weights, transposed
  ushort* mpt     = wet + 256 * 128;
  ushort* ne0t    = mpt + 4 * 65536;
  ushort* nwt     = ne0t + 256 * 512;

  hipMemsetAsync(counts, 0, (NLVL - 1) * PN * sizeof(int), stream);
  fill_csr_kernel<<<((NLVL - 1) * EPLE + 255) / 256, 256, 0, stream>>>(esrc, edst, counts, buckets);
  prep_w<<<1024, 256, 0, stream>>>(W_embed, mp_w, ne_w0, ne_w, wet, mpt, ne0t, nwt);
  embed0<<<(PN + 127) / 128, 256, 0, stream>>>(nf, wet, b_embed, out);
  for (int l = 0; l < NLVL - 1; ++l) {
    level_mfma<<<(PN + ROWS - 1) / ROWS, 512, 0, stream>>>(out, nf, counts, buckets,
                                                           wet, mpt, ne0t, nwt,
                                                           b_embed, mp_b, ne_b0, ne_b, l);
  }
}